// Round 14
// baseline (72.386 us; speedup 1.0000x reference)
//
#include <hip/hip_runtime.h>

typedef __bf16 bf16_t;
typedef __bf16 bf16x8 __attribute__((ext_vector_type(8)));
typedef __bf16 bf16x4 __attribute__((ext_vector_type(4)));
typedef float  f32x4  __attribute__((ext_vector_type(4)));
typedef _Float16 f16_t;
typedef _Float16 f16x8 __attribute__((ext_vector_type(8)));

#define TSEQ 4096
#define SEGS 8

// lgkm-only barrier: in-flight global prefetches survive it.
__device__ __forceinline__ void barrier_lds() {
    __builtin_amdgcn_sched_barrier(0);
    asm volatile("s_waitcnt lgkmcnt(0)" ::: "memory");
    __builtin_amdgcn_s_barrier();
    __builtin_amdgcn_sched_barrier(0);
}

// ---------------------------------------------------------------------------
// wsplit: W[1024][64] (q,k,v fp32) -> wT[192][1024] bf16 (transposed).
// Wq pre-scaled by 0.125*log2(e) so attention scores land in exp2 domain.
// ---------------------------------------------------------------------------
__global__ __launch_bounds__(256) void wsplit_k(
    const float* __restrict__ Wq, const float* __restrict__ Wk,
    const float* __restrict__ Wv, bf16_t* __restrict__ wT)
{
    __shared__ bf16_t th[64][72];
    const int mat = blockIdx.x >> 4;
    const int kb  = (blockIdx.x & 15) * 64;
    const float* W = (mat == 0) ? Wq : ((mat == 1) ? Wk : Wv);
    const float scale = (mat == 0) ? 0.18033688011112042f : 1.0f;
    const int t  = threadIdx.x;
    const int kl = t >> 2;
    const int dc = (t & 3) * 16;
    #pragma unroll
    for (int i = 0; i < 4; ++i) {
        float4 v = *reinterpret_cast<const float4*>(W + (long)(kb + kl) * 64 + dc + 4 * i);
        th[dc + 4*i + 0][kl] = (bf16_t)(v.x * scale);
        th[dc + 4*i + 1][kl] = (bf16_t)(v.y * scale);
        th[dc + 4*i + 2][kl] = (bf16_t)(v.z * scale);
        th[dc + 4*i + 3][kl] = (bf16_t)(v.w * scale);
    }
    __syncthreads();
    const int d  = t >> 2;
    const int kc = (t & 3) * 16;
    bf16x8 a0 = *reinterpret_cast<const bf16x8*>(&th[d][kc]);
    bf16x8 a1 = *reinterpret_cast<const bf16x8*>(&th[d][kc + 8]);
    long o = (long)(mat * 64 + d) * 1024 + kb + kc;
    *reinterpret_cast<bf16x8*>(wT + o)     = a0;
    *reinterpret_cast<bf16x8*>(wT + o + 8) = a1;
}

// ---------------------------------------------------------------------------
// proj v4: [8192][192] = X @ W^T.  ZERO LDS in the K-loop, ZERO barriers,
// fully self-paced waves (the r2/r5 proj counters showed latency/sync-bound,
// NOT traffic-bound: FETCH was only 19.5 MB).  512 blocks x 16 rows; 4
// waves; wave w owns N-tiles {w, w+4, w+8} (one 16-col tile of each of
// q,k,v).  A-frags cvt'd from X (all 4 waves share rows -> L1 reuse);
// B-frags read straight from wT (L2-resident, 384 KB).  32 K-steps,
// unroll-4 for memory-level parallelism.  Scalars only -> no scratch.
// ---------------------------------------------------------------------------
__global__ __launch_bounds__(256, 4) void proj_mfma(
    const float* __restrict__ X, const bf16_t* __restrict__ wT,
    bf16_t* __restrict__ qh, bf16_t* __restrict__ kh, bf16_t* __restrict__ vt)
{
    __shared__ float vtl[64][20];   // v-transpose staging (epilogue only)

    const int tid = threadIdx.x, lane = tid & 63;
    const int w   = tid >> 6;
    const int q4 = lane & 15, g = lane >> 4;
    const long R0 = (long)blockIdx.x * 16;

    const float*  xrow = X  + (R0 + q4) * 1024 + 8 * g;
    const bf16_t* wp0  = wT + (long)((w +  0) * 16 + q4) * 1024 + 8 * g;
    const bf16_t* wp1  = wT + (long)((w +  4) * 16 + q4) * 1024 + 8 * g;
    const bf16_t* wp2  = wT + (long)((w +  8) * 16 + q4) * 1024 + 8 * g;

    f32x4 acc0 = {}, acc1 = {}, acc2 = {};

    #pragma unroll 4
    for (int k0 = 0; k0 < 1024; k0 += 32) {
        float4 x0 = *reinterpret_cast<const float4*>(xrow + k0);
        float4 x1 = *reinterpret_cast<const float4*>(xrow + k0 + 4);
        bf16x8 b0 = *reinterpret_cast<const bf16x8*>(wp0 + k0);
        bf16x8 b1 = *reinterpret_cast<const bf16x8*>(wp1 + k0);
        bf16x8 b2 = *reinterpret_cast<const bf16x8*>(wp2 + k0);
        bf16x8 af = {(bf16_t)x0.x, (bf16_t)x0.y, (bf16_t)x0.z, (bf16_t)x0.w,
                     (bf16_t)x1.x, (bf16_t)x1.y, (bf16_t)x1.z, (bf16_t)x1.w};
        acc0 = __builtin_amdgcn_mfma_f32_16x16x32_bf16(af, b0, acc0, 0, 0, 0);
        acc1 = __builtin_amdgcn_mfma_f32_16x16x32_bf16(af, b1, acc1, 0, 0, 0);
        acc2 = __builtin_amdgcn_mfma_f32_16x16x32_bf16(af, b2, acc2, 0, 0, 0);
    }

    // epilogue: nt=w -> q tile w, nt=w+4 -> k tile w, nt=w+8 -> v tile w
    #pragma unroll
    for (int r = 0; r < 4; ++r) {
        const long row = R0 + 4 * g + r;
        qh[row * 64 + w * 16 + q4] = (bf16_t)acc0[r];
        kh[row * 64 + w * 16 + q4] = (bf16_t)acc1[r];
        vtl[w * 16 + q4][4 * g + r] = acc2[r];
    }
    __syncthreads();
    {
        const int d = tid >> 2, rc = (tid & 3) * 4;
        bf16x4 o;
        #pragma unroll
        for (int i = 0; i < 4; ++i) o[i] = (bf16_t)vtl[d][rc + i];
        *reinterpret_cast<bf16x4*>(vt + (long)d * 8192 + R0 + rc) = o;
    }
}

// ---------------------------------------------------------------------------
// attn (r6 version, best measured): flash, block = 64 queries (4 waves
// M-split), seg round-robin causal split.  K/V double-buffered in LDS,
// staged T14 (loads one chunk early); in-loop barrier lgkm-only.  exp2.
// ---------------------------------------------------------------------------
__global__ __launch_bounds__(256, 3) void attn_mfma(
    const bf16_t* __restrict__ qh, const bf16_t* __restrict__ kh,
    const bf16_t* __restrict__ vt,
    f16_t* __restrict__ pO, float* __restrict__ pm, float* __restrict__ pl)
{
    __shared__ __align__(16) unsigned char smem[46080];
    bf16_t (*kl)[64][72]  = reinterpret_cast<bf16_t(*)[64][72]>(smem);           // [2]
    bf16_t (*vl)[64][72]  = reinterpret_cast<bf16_t(*)[64][72]>(smem + 18432);   // [2]
    bf16_t (*P)[8][16][8] = reinterpret_cast<bf16_t(*)[8][16][8]>(smem + 36864); // [4]
    f16_t  (*ot)[16][72]  = reinterpret_cast<f16_t(*)[16][72]>(smem + 36864);    // [4] union

    const int tid = threadIdx.x, lane = tid & 63, w = tid >> 6;
    const int q4 = lane & 15, g = lane >> 4;
    const int bx = blockIdx.x, b = blockIdx.y;
    const int tile = 63 - (bx >> 3);     // heavy tiles first
    const int seg  = bx & 7;
    const int C = tile + 1;
    if (seg >= C) return;
    const long base = (long)b * TSEQ;
    const int r0 = tile * 64 + 16 * w;

    const bf16_t* qr = qh + (base + r0 + q4) * 64 + 8 * g;
    const bf16x8 qf0 = *reinterpret_cast<const bf16x8*>(qr);
    const bf16x8 qf1 = *reinterpret_cast<const bf16x8*>(qr + 32);

    const int srow = tid >> 2, sc = (tid & 3) * 16;
    const bf16_t* ksrc = kh + (base + srow) * 64 + sc;
    const bf16_t* vsrc = vt + (long)srow * 8192 + base + sc;
    bf16x8 kr0, kr1, vr0, vr1;
    auto loadKV = [&](int kb) {
        kr0 = *reinterpret_cast<const bf16x8*>(ksrc + (long)kb * 64);
        kr1 = *reinterpret_cast<const bf16x8*>(ksrc + (long)kb * 64 + 8);
        vr0 = *reinterpret_cast<const bf16x8*>(vsrc + kb);
        vr1 = *reinterpret_cast<const bf16x8*>(vsrc + kb + 8);
    };
    auto writeKV = [&](int buf) {
        *reinterpret_cast<bf16x8*>(&kl[buf][srow][sc])     = kr0;
        *reinterpret_cast<bf16x8*>(&kl[buf][srow][sc + 8]) = kr1;
        *reinterpret_cast<bf16x8*>(&vl[buf][srow][sc])     = vr0;
        *reinterpret_cast<bf16x8*>(&vl[buf][srow][sc + 8]) = vr1;
    };

    float m = -1e30f, l = 0.f;
    f32x4 oacc[4] = {};

    loadKV(seg << 6);
    writeKV(0);
    { int c1 = seg + SEGS; loadKV((c1 < C ? c1 : seg) << 6); }
    asm volatile("" ::: "memory");
    barrier_lds();

    int i = 0;
    for (int c = seg; c < C; c += SEGS, ++i) {
        const int buf = i & 1;
        if (c + SEGS < C) {
            writeKV(buf ^ 1);
            int cn = c + 2 * SEGS;
            loadKV((cn < C ? cn : c + SEGS) << 6);
            asm volatile("" ::: "memory");
        }
        const int kb = c << 6;

        f32x4 sacc[4];
        __builtin_amdgcn_s_setprio(1);
        #pragma unroll
        for (int kt = 0; kt < 4; ++kt) {
            bf16x8 kf0 = *reinterpret_cast<const bf16x8*>(&kl[buf][kt * 16 + q4][8 * g]);
            bf16x8 kf1 = *reinterpret_cast<const bf16x8*>(&kl[buf][kt * 16 + q4][8 * g + 32]);
            f32x4 a = {};
            a = __builtin_amdgcn_mfma_f32_16x16x32_bf16(kf0, qf0, a, 0, 0, 0);
            a = __builtin_amdgcn_mfma_f32_16x16x32_bf16(kf1, qf1, a, 0, 0, 0);
            sacc[kt] = a;
        }
        __builtin_amdgcn_s_setprio(0);

        float p[16];
        const bool diag = (c == C - 1);
        float mx = -1e30f;
        #pragma unroll
        for (int kt = 0; kt < 4; ++kt)
            #pragma unroll
            for (int r = 0; r < 4; ++r) {
                float sv = sacc[kt][r];
                if (diag && (kb + kt * 16 + 4 * g + r > r0 + q4)) sv = -1e30f;
                p[kt * 4 + r] = sv;
                mx = fmaxf(mx, sv);
            }
        mx = fmaxf(mx, __shfl_xor(mx, 16));
        mx = fmaxf(mx, __shfl_xor(mx, 32));
        const float mnew = fmaxf(m, mx);
        const float alpha = __builtin_exp2f(m - mnew);
        m = mnew;
        float lsum = 0.f;
        #pragma unroll
        for (int ii = 0; ii < 16; ++ii) { p[ii] = __builtin_exp2f(p[ii] - mnew); lsum += p[ii]; }
        lsum += __shfl_xor(lsum, 16);
        lsum += __shfl_xor(lsum, 32);
        l = l * alpha + lsum;
        #pragma unroll
        for (int dt = 0; dt < 4; ++dt) oacc[dt] *= alpha;

        #pragma unroll
        for (int kt = 0; kt < 4; ++kt) {
            const int cb = 2 * kt + (g >> 1);
            const int ki = (g & 1) << 2;
            bf16x4 hv = {(bf16_t)p[4*kt+0], (bf16_t)p[4*kt+1],
                         (bf16_t)p[4*kt+2], (bf16_t)p[4*kt+3]};
            *reinterpret_cast<bf16x4*>(&P[w][cb][q4][ki]) = hv;
        }
        bf16x8 ph0 = *reinterpret_cast<const bf16x8*>(&P[w][g][q4][0]);
        bf16x8 ph1 = *reinterpret_cast<const bf16x8*>(&P[w][4 + g][q4][0]);
        __builtin_amdgcn_s_setprio(1);
        #pragma unroll
        for (int dt = 0; dt < 4; ++dt) {
            bf16x8 va0 = *reinterpret_cast<const bf16x8*>(&vl[buf][dt * 16 + q4][8 * g]);
            bf16x8 va1 = *reinterpret_cast<const bf16x8*>(&vl[buf][dt * 16 + q4][8 * g + 32]);
            oacc[dt] = __builtin_amdgcn_mfma_f32_16x16x32_bf16(va0, ph0, oacc[dt], 0, 0, 0);
            oacc[dt] = __builtin_amdgcn_mfma_f32_16x16x32_bf16(va1, ph1, oacc[dt], 0, 0, 0);
        }
        __builtin_amdgcn_s_setprio(0);
        barrier_lds();
    }

    const float invl = 1.0f / l;
    #pragma unroll
    for (int dt = 0; dt < 4; ++dt)
        #pragma unroll
        for (int r = 0; r < 4; ++r)
            ot[w][q4][dt * 16 + 4 * g + r] = (f16_t)(oacc[dt][r] * invl);

    const long pbase = (((long)b * 64 + tile) * SEGS + seg) * 64;
    {
        const int q  = lane >> 2;
        const int dc = (lane & 3) * 16;
        f16x8 o0 = *reinterpret_cast<const f16x8*>(&ot[w][q][dc]);
        f16x8 o1 = *reinterpret_cast<const f16x8*>(&ot[w][q][dc + 8]);
        f16_t* dst = pO + (pbase + 16 * w + q) * 64 + dc;
        *reinterpret_cast<f16x8*>(dst)     = o0;
        *reinterpret_cast<f16x8*>(dst + 8) = o1;
    }
    if (g == 0) {
        pm[pbase + 16 * w + q4] = m;
        pl[pbase + 16 * w + q4] = l;
    }
}

// ---------------------------------------------------------------------------
// merge: combine active segs per 64q tile -> final O (fp32).  exp2 domain.
// ---------------------------------------------------------------------------
__global__ __launch_bounds__(256) void merge_k(
    const f16_t* __restrict__ pO, const float* __restrict__ pm,
    const float* __restrict__ pl, float* __restrict__ O)
{
    const int tile = blockIdx.x, b = blockIdx.y;
    const int C = tile + 1;
    const int S = (C < SEGS) ? C : SEGS;
    const int t = threadIdx.x;
    const int q = t >> 2, dc = (t & 3) * 16;
    const long pb = ((long)b * 64 + tile) * SEGS;

    float mstar = -1e30f;
    for (int s = 0; s < S; ++s) mstar = fmaxf(mstar, pm[(pb + s) * 64 + q]);
    float L = 0.f;
    float o[16];
    #pragma unroll
    for (int i = 0; i < 16; ++i) o[i] = 0.f;
    for (int s = 0; s < S; ++s) {
        const float ws = __builtin_exp2f(pm[(pb + s) * 64 + q] - mstar) * pl[(pb + s) * 64 + q];
        L += ws;
        const f16_t* src = pO + ((pb + s) * 64 + q) * 64 + dc;
        f16x8 a0 = *reinterpret_cast<const f16x8*>(src);
        f16x8 a1 = *reinterpret_cast<const f16x8*>(src + 8);
        #pragma unroll
        for (int i = 0; i < 8; ++i) {
            o[i]     += ws * (float)a0[i];
            o[8 + i] += ws * (float)a1[i];
        }
    }
    const float inv = 1.0f / L;
    float* dst = O + ((long)b * TSEQ + tile * 64 + q) * 64 + dc;
    #pragma unroll
    for (int i = 0; i < 4; ++i) {
        f32x4 v = {o[4*i] * inv, o[4*i+1] * inv, o[4*i+2] * inv, o[4*i+3] * inv};
        *reinterpret_cast<f32x4*>(dst + 4 * i) = v;
    }
}

extern "C" void kernel_launch(void* const* d_in, const int* in_sizes, int n_in,
                              void* d_out, int out_size, void* d_ws, size_t ws_size,
                              hipStream_t stream)
{
    const float* X  = (const float*)d_in[0];
    const float* Wq = (const float*)d_in[1];
    const float* Wk = (const float*)d_in[2];
    const float* Wv = (const float*)d_in[3];
    float* O = (float*)d_out;

    char* ws = (char*)d_ws;
    size_t off = 0;
    bf16_t* wT = (bf16_t*)(ws + off); off += 192 * 1024 * sizeof(bf16_t);
    bf16_t* qh = (bf16_t*)(ws + off); off += 8192L * 64 * sizeof(bf16_t);
    bf16_t* kh = (bf16_t*)(ws + off); off += 8192L * 64 * sizeof(bf16_t);
    bf16_t* vt = (bf16_t*)(ws + off); off += 64L * 8192 * sizeof(bf16_t);
    f16_t*  pO = (f16_t*)(ws + off);  off += 2L * 64 * SEGS * 64 * 64 * sizeof(f16_t);
    float*  pm = (float*)(ws + off);  off += 2L * 64 * SEGS * 64 * sizeof(float);
    float*  pl = (float*)(ws + off);  off += 2L * 64 * SEGS * 64 * sizeof(float);

    wsplit_k <<<48, 256, 0, stream>>>(Wq, Wk, Wv, wT);
    proj_mfma<<<512, 256, 0, stream>>>(X, wT, qh, kh, vt);
    attn_mfma<<<dim3(512, 2), 256, 0, stream>>>(qh, kh, vt, pO, pm, pl);
    merge_k  <<<dim3(64, 2), 256, 0, stream>>>(pO, pm, pl, O);
}